// Round 6
// baseline (447.185 us; speedup 1.0000x reference)
//
#include <hip/hip_runtime.h>
#include <math.h>
#include <stdint.h>

#define B_   2
#define S_   2048
#define E_   1024
#define NH   16
#define DH   64
#define HID  512
#define NCAT 3584            // Q(1024) + K(1024) + V(1024) + h(512)
#define MTOK 4096            // B_*S_

typedef unsigned short ushort_t;
typedef short  s16x8  __attribute__((ext_vector_type(8)));
typedef unsigned short us4 __attribute__((ext_vector_type(4)));
typedef float  f32x4  __attribute__((ext_vector_type(4)));

static constexpr float LN_EPS    = 1e-5f;
static constexpr float SCALE     = 0.125f;   // Dh^-0.5
static constexpr float INV_SQRT2 = 0.70710678118654752440f;

__device__ __forceinline__ float gelu_exact(float v) {
    return 0.5f * v * (1.0f + erff(v * INV_SQRT2));
}

// fp32 <-> bf16 bits (RNE)
__device__ __forceinline__ ushort_t f2bf(float f) {
    unsigned int u = __float_as_uint(f);
    unsigned int r = u + 0x7fffu + ((u >> 16) & 1u);
    return (ushort_t)(r >> 16);
}
__device__ __forceinline__ float bf2f(ushort_t s) {
    return __uint_as_float(((unsigned int)s) << 16);
}

// async global->LDS 16B per lane; LDS dest is wave-uniform base + lane*16
__device__ __forceinline__ void stage16(const void* g, void* ldsbase) {
#if __has_builtin(__builtin_amdgcn_global_load_lds)
    __builtin_amdgcn_global_load_lds(
        (const __attribute__((address_space(1))) void*)g,
        (__attribute__((address_space(3))) void*)ldsbase, 16, 0, 0);
#else
    ((uint4*)ldsbase)[threadIdx.x & 63] = *(const uint4*)g;
#endif
}

// T1: XCD-chunked bijective block swizzle (requires total % 8 == 0).
__device__ __forceinline__ void xcd_swizzle(int gx, int gy, int& bx, int& by) {
    const int T = gx * gy;
    const int lin = blockIdx.y * gx + blockIdx.x;
    const int work = (lin & 7) * (T >> 3) + (lin >> 3);
    bx = work % gx;
    by = work / gx;
}

// ---------------------------------------------------------------------------
// fp32 -> bf16 hi/lo split (x)
// ---------------------------------------------------------------------------
__global__ __launch_bounds__(256) void split_kernel(
    const float* __restrict__ src, ushort_t* __restrict__ dh,
    ushort_t* __restrict__ dl, int n4)
{
    int i = blockIdx.x * 256 + threadIdx.x;
    if (i >= n4) return;
    float4 v = ((const float4*)src)[i];
    float vv[4] = {v.x, v.y, v.z, v.w};
    us4 h, l;
    #pragma unroll
    for (int j = 0; j < 4; ++j) {
        ushort_t hh = f2bf(vv[j]);
        h[j] = hh;
        l[j] = f2bf(vv[j] - bf2f(hh));
    }
    *(us4*)&dh[i * 4] = h;
    *(us4*)&dl[i * 4] = l;
}

// ---------------------------------------------------------------------------
// W [1024][N] fp32  ->  W^T [N][1024] bf16 hi/lo   (32x32 tiles via LDS)
// ---------------------------------------------------------------------------
__global__ __launch_bounds__(256) void transpose_split_kernel(
    const float* __restrict__ W, int N,
    ushort_t* __restrict__ th, ushort_t* __restrict__ tl)
{
    __shared__ float tile[32][33];
    const int k0 = blockIdx.x * 32, n0 = blockIdx.y * 32;
    const int t = threadIdx.x;
    const int r = t >> 3, c4 = (t & 7) * 4;

    float4 v = *(const float4*)&W[(size_t)(k0 + r) * N + n0 + c4];
    tile[r][c4 + 0] = v.x; tile[r][c4 + 1] = v.y;
    tile[r][c4 + 2] = v.z; tile[r][c4 + 3] = v.w;
    __syncthreads();

    us4 h, l;
    #pragma unroll
    for (int i = 0; i < 4; ++i) {
        float x = tile[c4 + i][r];
        ushort_t hh = f2bf(x);
        h[i] = hh;
        l[i] = f2bf(x - bf2f(hh));
    }
    *(us4*)&th[(size_t)(n0 + r) * E_ + k0 + c4] = h;
    *(us4*)&tl[(size_t)(n0 + r) * E_ + k0 + c4] = l;
}

__global__ void concat_bias_kernel(
    const float* __restrict__ bq, const float* __restrict__ bk,
    const float* __restrict__ bv, const float* __restrict__ b1,
    float* __restrict__ bcat)
{
    int i = blockIdx.x * 256 + threadIdx.x;
    if (i >= NCAT) return;
    float v;
    if      (i < 1024) v = bq[i];
    else if (i < 2048) v = bk[i - 1024];
    else if (i < 3072) v = bv[i - 2048];
    else               v = b1[i - 3072];
    bcat[i] = v;
}

// ---------------------------------------------------------------------------
// Shared GEMM core: 128x128 tile, BK=32, 4 waves, bf16x3 MFMA emulation,
// m97 structure (global_load_lds 16B staging).  acc = (Ah+Al)(Bh+Bl)^T.
// ---------------------------------------------------------------------------
struct GemmCtx {
    int lane, w, wr, wc;
};

__device__ __forceinline__ void gemm_core(
    const ushort_t* __restrict__ Ah, const ushort_t* __restrict__ Al,
    const ushort_t* __restrict__ Bh, const ushort_t* __restrict__ Bl,
    int row0, int col0, int Kd,
    ushort_t* Ahs, ushort_t* Als, ushort_t* Bhs, ushort_t* Bls,
    f32x4 (&acc)[4][4], const GemmCtx& cx)
{
    const int lr = cx.lane >> 2;          // row within 16-row staging chunk
    const int lc = (cx.lane & 3) * 8;     // bf16 col offset (16B chunk)

    for (int k0 = 0; k0 < Kd; k0 += 32) {
        #pragma unroll
        for (int ii = 0; ii < 2; ++ii) {
            const int r0 = (cx.w * 2 + ii) * 16;
            const size_t ga = (size_t)(row0 + r0 + lr) * Kd + k0 + lc;
            const size_t gb = (size_t)(col0 + r0 + lr) * Kd + k0 + lc;
            stage16(Ah + ga, &Ahs[r0 * 32]);
            stage16(Al + ga, &Als[r0 * 32]);
            stage16(Bh + gb, &Bhs[r0 * 32]);
            stage16(Bl + gb, &Bls[r0 * 32]);
        }
        __syncthreads();

        const int rA = cx.wr * 64 + (cx.lane & 15);
        const int rB = cx.wc * 64 + (cx.lane & 15);
        const int kq = (cx.lane >> 4) * 8;
        s16x8 fah[4], fal[4], fbh[4], fbl[4];
        #pragma unroll
        for (int i = 0; i < 4; ++i) {
            fah[i] = *(const s16x8*)&Ahs[(rA + i * 16) * 32 + kq];
            fal[i] = *(const s16x8*)&Als[(rA + i * 16) * 32 + kq];
            fbh[i] = *(const s16x8*)&Bhs[(rB + i * 16) * 32 + kq];
            fbl[i] = *(const s16x8*)&Bls[(rB + i * 16) * 32 + kq];
        }
        __builtin_amdgcn_s_setprio(1);
        #pragma unroll
        for (int i = 0; i < 4; ++i)
            #pragma unroll
            for (int j = 0; j < 4; ++j) {
                acc[i][j] = __builtin_amdgcn_mfma_f32_16x16x32_bf16(fah[i], fbh[j], acc[i][j], 0, 0, 0);
                acc[i][j] = __builtin_amdgcn_mfma_f32_16x16x32_bf16(fah[i], fbl[j], acc[i][j], 0, 0, 0);
                acc[i][j] = __builtin_amdgcn_mfma_f32_16x16x32_bf16(fal[i], fbh[j], acc[i][j], 0, 0, 0);
            }
        __builtin_amdgcn_s_setprio(0);
        __syncthreads();
    }
}

// ---------------------------------------------------------------------------
// GEMM1: x @ [Wq|Wk|Wv|dp_w1] with fused routing epilogue:
//   cols [0,1024)    -> Q bf16 hi/lo, pre-scaled by Dh^-0.5
//   cols [1024,2048) -> K bf16 hi/lo
//   cols [2048,3072) -> V fp32 (compact, gate applied later)
//   cols [3072,3584) -> h fp32 (compact, drift-probe input)
// ---------------------------------------------------------------------------
__global__ __launch_bounds__(256) void mfma_gemm_qkvh_kernel(
    const ushort_t* __restrict__ Ah, const ushort_t* __restrict__ Al,
    const ushort_t* __restrict__ Bh, const ushort_t* __restrict__ Bl,
    const float* __restrict__ bias,
    ushort_t* __restrict__ Qh, ushort_t* __restrict__ Ql,
    ushort_t* __restrict__ Kh, ushort_t* __restrict__ Kl,
    float* __restrict__ v32, float* __restrict__ h32)
{
    __shared__ __align__(16) ushort_t Ahs[128 * 32];
    __shared__ __align__(16) ushort_t Als[128 * 32];
    __shared__ __align__(16) ushort_t Bhs[128 * 32];
    __shared__ __align__(16) ushort_t Bls[128 * 32];

    int bx, by;
    xcd_swizzle(28, 32, bx, by);               // 896 blocks = 8 x 112
    const int row0 = by * 128, col0 = bx * 128;

    GemmCtx cx;
    cx.lane = threadIdx.x & 63;
    cx.w    = threadIdx.x >> 6;
    cx.wr   = cx.w >> 1; cx.wc = cx.w & 1;

    f32x4 acc[4][4] = {};
    gemm_core(Ah, Al, Bh, Bl, row0, col0, E_, Ahs, Als, Bhs, Bls, acc, cx);

    // C/D layout: col = lane&15, row = (lane>>4)*4 + reg   [m89/m91]
    const int crow = row0 + cx.wr * 64 + ((cx.lane >> 4) * 4);
    const int ccol0 = col0 + cx.wc * 64 + (cx.lane & 15);

    #pragma unroll
    for (int j = 0; j < 4; ++j) {
        const int gcol = ccol0 + j * 16;
        const float bv = bias[gcol];
        #pragma unroll
        for (int i = 0; i < 4; ++i)
            #pragma unroll
            for (int r = 0; r < 4; ++r) {
                const int row = crow + i * 16 + r;
                float val = acc[i][j][r] + bv;
                if (gcol < 1024) {            // Q (pre-scaled)
                    val *= SCALE;
                    ushort_t hi = f2bf(val);
                    Qh[(size_t)row * 1024 + gcol] = hi;
                    Ql[(size_t)row * 1024 + gcol] = f2bf(val - bf2f(hi));
                } else if (gcol < 2048) {     // K
                    ushort_t hi = f2bf(val);
                    Kh[(size_t)row * 1024 + gcol - 1024] = hi;
                    Kl[(size_t)row * 1024 + gcol - 1024] = f2bf(val - bf2f(hi));
                } else if (gcol < 3072) {     // V (fp32; gate folded later)
                    v32[(size_t)row * 1024 + gcol - 2048] = val;
                } else {                      // h (drift-probe)
                    h32[(size_t)row * 512 + gcol - 3072] = val;
                }
            }
    }
}

// ---------------------------------------------------------------------------
// GEMM2 (Wo): plain fp32-out GEMM with bias
// ---------------------------------------------------------------------------
__global__ __launch_bounds__(256) void mfma_gemm_kernel(
    const ushort_t* __restrict__ Ah, const ushort_t* __restrict__ Al,
    const ushort_t* __restrict__ Bh, const ushort_t* __restrict__ Bl,
    const float* __restrict__ bias,
    float* __restrict__ C, int N, int Kd)
{
    __shared__ __align__(16) ushort_t Ahs[128 * 32];
    __shared__ __align__(16) ushort_t Als[128 * 32];
    __shared__ __align__(16) ushort_t Bhs[128 * 32];
    __shared__ __align__(16) ushort_t Bls[128 * 32];

    int bx, by;
    xcd_swizzle(gridDim.x, gridDim.y, bx, by);
    const int row0 = by * 128, col0 = bx * 128;

    GemmCtx cx;
    cx.lane = threadIdx.x & 63;
    cx.w    = threadIdx.x >> 6;
    cx.wr   = cx.w >> 1; cx.wc = cx.w & 1;

    f32x4 acc[4][4] = {};
    gemm_core(Ah, Al, Bh, Bl, row0, col0, Kd, Ahs, Als, Bhs, Bls, acc, cx);

    const int crow = row0 + cx.wr * 64 + ((cx.lane >> 4) * 4);
    const int ccol = col0 + cx.wc * 64 + (cx.lane & 15);
    #pragma unroll
    for (int j = 0; j < 4; ++j) {
        const float bv = bias[ccol + j * 16];
        #pragma unroll
        for (int i = 0; i < 4; ++i)
            #pragma unroll
            for (int r = 0; r < 4; ++r)
                C[(size_t)(crow + i * 16 + r) * N + ccol + j * 16] = acc[i][j][r] + bv;
    }
}

// ---------------------------------------------------------------------------
// Per-row drift tail: LN(h32) -> GELU -> @dp_w2 -> tiny MLP -> tanh = gate
// ---------------------------------------------------------------------------
__global__ __launch_bounds__(256) void ln_gate_kernel(
    const float* __restrict__ h32,
    const float* __restrict__ lng, const float* __restrict__ lnb,
    const float* __restrict__ w2,  const float* __restrict__ b2,
    const float* __restrict__ gw1, const float* __restrict__ gb1,
    const float* __restrict__ gw2, const float* __restrict__ gb2,
    float* __restrict__ gate)
{
    const int row  = blockIdx.x * 4 + (threadIdx.x >> 6);
    const int lane = threadIdx.x & 63;
    const float* h = h32 + (size_t)row * 512;

    float4 a = *(const float4*)&h[lane * 4];
    float4 b = *(const float4*)&h[256 + lane * 4];
    float va[8] = {a.x, a.y, a.z, a.w, b.x, b.y, b.z, b.w};

    float sum = 0.f, sq = 0.f;
    #pragma unroll
    for (int j = 0; j < 8; ++j) { sum += va[j]; sq += va[j] * va[j]; }
    #pragma unroll
    for (int o = 1; o < 64; o <<= 1) {
        sum += __shfl_xor(sum, o);
        sq  += __shfl_xor(sq,  o);
    }
    const float mu  = sum * (1.f / HID);
    const float inv = 1.f / sqrtf(sq * (1.f / HID) - mu * mu + LN_EPS);

    float4 g0 = *(const float4*)&lng[lane * 4];
    float4 g1 = *(const float4*)&lng[256 + lane * 4];
    float4 o0 = *(const float4*)&lnb[lane * 4];
    float4 o1 = *(const float4*)&lnb[256 + lane * 4];
    float4 w0 = *(const float4*)&w2[lane * 4];
    float4 w1 = *(const float4*)&w2[256 + lane * 4];
    float gg[8] = {g0.x, g0.y, g0.z, g0.w, g1.x, g1.y, g1.z, g1.w};
    float bb[8] = {o0.x, o0.y, o0.z, o0.w, o1.x, o1.y, o1.z, o1.w};
    float ww[8] = {w0.x, w0.y, w0.z, w0.w, w1.x, w1.y, w1.z, w1.w};

    float part = 0.f;
    #pragma unroll
    for (int j = 0; j < 8; ++j) {
        float nx = (va[j] - mu) * inv * gg[j] + bb[j];
        part += gelu_exact(nx) * ww[j];
    }
    #pragma unroll
    for (int o = 1; o < 64; o <<= 1) part += __shfl_xor(part, o);

    if (lane == 0) {
        float drift = part + b2[0];
        float gacc = gb2[0];
        #pragma unroll
        for (int i = 0; i < 16; ++i) {
            float t = fmaf(drift, gw1[i], gb1[i]);
            gacc = fmaf(gelu_exact(t), gw2[i], gacc);
        }
        gate[row] = tanhf(gacc);
    }
}

// ---------------------------------------------------------------------------
// v32 [4096][1024] -> gated, transposed per head: Vt[bh][d=64][S=2048] hi/lo
// ---------------------------------------------------------------------------
__global__ __launch_bounds__(256) void v_transpose_kernel(
    const float* __restrict__ v32, const float* __restrict__ gate,
    ushort_t* __restrict__ Vth, ushort_t* __restrict__ Vtl)
{
    __shared__ float T[64 * 68];
    const int kt = blockIdx.x, bh = blockIdx.y;
    const int b = bh >> 4, h = bh & 15;
    const int tid = threadIdx.x;

    #pragma unroll
    for (int it = 0; it < 4; ++it) {
        int idx = tid + it * 256;                  // 0..1023
        int tokr = idx >> 4, f4 = idx & 15;
        int tok = b * S_ + kt * 64 + tokr;
        float g = gate[tok];
        float4 v = *(const float4*)&v32[(size_t)tok * 1024 + h * 64 + f4 * 4];
        T[(f4 * 4 + 0) * 68 + tokr] = v.x * g;
        T[(f4 * 4 + 1) * 68 + tokr] = v.y * g;
        T[(f4 * 4 + 2) * 68 + tokr] = v.z * g;
        T[(f4 * 4 + 3) * 68 + tokr] = v.w * g;
    }
    __syncthreads();

    const int d = tid >> 2, t0 = (tid & 3) * 16;
    const size_t obase = (size_t)bh * 64 * S_ + (size_t)d * S_ + kt * 64 + t0;
    s16x8 h8[2], l8[2];
    #pragma unroll
    for (int u = 0; u < 16; ++u) {
        float f = T[d * 68 + t0 + u];
        ushort_t hh = f2bf(f);
        h8[u >> 3][u & 7] = (short)hh;
        l8[u >> 3][u & 7] = (short)f2bf(f - bf2f(hh));
    }
    *(s16x8*)&Vth[obase]     = h8[0];
    *(s16x8*)&Vth[obase + 8] = h8[1];
    *(s16x8*)&Vtl[obase]     = l8[0];
    *(s16x8*)&Vtl[obase + 8] = l8[1];
}

// ---------------------------------------------------------------------------
// MFMA causal flash attention (bf16 hi/lo x3 emu).
// v2: QB=128, 8 waves (512 thr).  K/V LDS shared by 8 waves; Ps aliased onto
// the dead Q-staging region -> 72 KB LDS -> 2 blocks/CU -> 16 waves/CU.
// T1 XCD swizzle (512 = 8x64); T14 K/V reg-prefetch; T5 setprio;
// per-wave causal tile skip.  Per-q arithmetic identical to v1 (validated).
// ---------------------------------------------------------------------------
__global__ __launch_bounds__(512, 4) void attn_mfma_kernel(
    const ushort_t* __restrict__ Qh, const ushort_t* __restrict__ Ql,
    const ushort_t* __restrict__ Kh, const ushort_t* __restrict__ Kl,
    const ushort_t* __restrict__ Vth, const ushort_t* __restrict__ Vtl,
    ushort_t* __restrict__ ch, ushort_t* __restrict__ cl)
{
    // carve one block: Q region [128][72] h/l (36864 B, dead after frag
    // hoist -> aliased by Ps: 8 waves x 16x68 u32 = 34816 B), K/V [64][72] h/l.
    __shared__ __align__(16) ushort_t smem[36864];   // 73728 B total
    ushort_t* const Qhs = smem;                      // [128][72]
    ushort_t* const Qls = smem + 9216;
    ushort_t* const Khs = smem + 18432;              // [64][72]
    ushort_t* const Kls = smem + 23040;
    ushort_t* const Vhs = smem + 27648;
    ushort_t* const Vls = smem + 32256;
    unsigned int* const Ps = (unsigned int*)smem;    // alias Q region

    const int tid  = threadIdx.x;
    const int lane = tid & 63;
    const int w    = tid >> 6;       // 0..7
    const int g    = lane >> 4;      // 0..3
    const int c    = lane & 15;      // 0..15

    // T1: 512 blocks = 8 XCD chunks of 64; each XCD gets 4 bh's full q-range.
    const int lin  = blockIdx.y * 16 + blockIdx.x;
    const int work = (lin & 7) * 64 + (lin >> 3);
    const int bh   = work >> 4;
    const int qt   = 15 - (work & 15);             // heavy diagonal first
    const int b    = bh >> 4, h = bh & 15;
    const int q0   = qt * 128;

    const size_t qkb = (size_t)b * S_ * 1024 + h * 64;   // [token][1024] slice
    const size_t vtb = (size_t)bh * 64 * S_;             // [d][2048]

    // stage Q tile (128 rows) into padded LDS: 1024 slots / 512 threads
    #pragma unroll
    for (int it = 0; it < 2; ++it) {
        int c2 = tid + it * 512;               // 0..1023
        int row = c2 >> 3, sl = c2 & 7;
        s16x8 vh = *(const s16x8*)&Qh[qkb + (size_t)(q0 + row) * 1024 + sl * 8];
        s16x8 vl = *(const s16x8*)&Ql[qkb + (size_t)(q0 + row) * 1024 + sl * 8];
        *(s16x8*)&Qhs[row * 72 + sl * 8] = vh;
        *(s16x8*)&Qls[row * 72 + sl * 8] = vl;
    }

    f32x4 o4[4] = {};
    float m[4], l[4];
    #pragma unroll
    for (int r = 0; r < 4; ++r) { m[r] = -INFINITY; l[r] = 0.f; }

    const int pbase = w * (16 * 68);
    __syncthreads();                           // Q visible to all waves

    // hoisted loop-invariant Q fragments (Q LDS dead afterwards)
    s16x8 qfh[2], qfl[2];
    #pragma unroll
    for (int ks = 0; ks < 2; ++ks) {
        qfh[ks] = *(const s16x8*)&Qhs[(w * 16 + c) * 72 + ks * 32 + g * 8];
        qfl[ks] = *(const s16x8*)&Qls[(w * 16 + c) * 72 + ks * 32 + g * 8];
    }

    const int srow = tid >> 3, ssl = tid & 7;   // staging: 512 slots = 64x8

    // prefetch K/V tile 0 into registers (T14)
    s16x8 pkh, pkl, pvh, pvl;
    pkh = *(const s16x8*)&Kh [qkb + (size_t)srow * 1024 + ssl * 8];
    pkl = *(const s16x8*)&Kl [qkb + (size_t)srow * 1024 + ssl * 8];
    pvh = *(const s16x8*)&Vth[vtb + (size_t)srow * S_ + ssl * 8];
    pvl = *(const s16x8*)&Vtl[vtb + (size_t)srow * S_ + ssl * 8];

    const int ktmax = 2 * qt + 1;              // keys up to q0+127
    const int qwave = q0 + w * 16;             // wave's first q row

    for (int kt = 0; kt <= ktmax; ++kt) {
        const int k0 = kt * 64;
        // write prefetched K/V registers to LDS (Q-frag reads already drained
        // by the barrier below on iter 0; later iters by loop-end barrier)
        *(s16x8*)&Khs[srow * 72 + ssl * 8] = pkh;
        *(s16x8*)&Kls[srow * 72 + ssl * 8] = pkl;
        *(s16x8*)&Vhs[srow * 72 + ssl * 8] = pvh;
        *(s16x8*)&Vls[srow * 72 + ssl * 8] = pvl;
        __syncthreads();

        // T14: issue next-tile loads; latency hides under this tile's compute
        if (kt < ktmax) {
            const int kn = k0 + 64;
            pkh = *(const s16x8*)&Kh [qkb + (size_t)(kn + srow) * 1024 + ssl * 8];
            pkl = *(const s16x8*)&Kl [qkb + (size_t)(kn + srow) * 1024 + ssl * 8];
            pvh = *(const s16x8*)&Vth[vtb + (size_t)srow * S_ + kn + ssl * 8];
            pvl = *(const s16x8*)&Vtl[vtb + (size_t)srow * S_ + kn + ssl * 8];
        }

        // per-wave causal skip: this wave's rows see no keys in this tile
        if (k0 <= qwave + 15) {
            // ---- S = Q K^T (wave's 16 q-rows x 64 keys), 3-MFMA emu ----
            f32x4 s4[4] = {};
            __builtin_amdgcn_s_setprio(1);
            #pragma unroll
            for (int j = 0; j < 4; ++j)
                #pragma unroll
                for (int ks = 0; ks < 2; ++ks) {
                    s16x8 kfh = *(const s16x8*)&Khs[(c + j * 16) * 72 + ks * 32 + g * 8];
                    s16x8 kfl = *(const s16x8*)&Kls[(c + j * 16) * 72 + ks * 32 + g * 8];
                    s4[j] = __builtin_amdgcn_mfma_f32_16x16x32_bf16(qfh[ks], kfh, s4[j], 0, 0, 0);
                    s4[j] = __builtin_amdgcn_mfma_f32_16x16x32_bf16(qfh[ks], kfl, s4[j], 0, 0, 0);
                    s4[j] = __builtin_amdgcn_mfma_f32_16x16x32_bf16(qfl[ks], kfh, s4[j], 0, 0, 0);
                }
            __builtin_amdgcn_s_setprio(0);

            // causal mask on overlapping tiles
            if (k0 + 63 > qwave) {
                #pragma unroll
                for (int j = 0; j < 4; ++j)
                    #pragma unroll
                    for (int r = 0; r < 4; ++r)
                        if (k0 + c + j * 16 > qwave + g * 4 + r)
                            s4[j][r] = -INFINITY;
            }

            // ---- online softmax: row r (q = g*4+r), 64 keys across j x c ----
            #pragma unroll
            for (int r = 0; r < 4; ++r) {
                float mx = fmaxf(fmaxf(s4[0][r], s4[1][r]), fmaxf(s4[2][r], s4[3][r]));
                #pragma unroll
                for (int o = 1; o < 16; o <<= 1) mx = fmaxf(mx, __shfl_xor(mx, o));
                float mn = fmaxf(m[r], mx);
                float corr = (m[r] == -INFINITY) ? 0.f : __expf(m[r] - mn);
                float ps = 0.f;
                #pragma unroll
                for (int j = 0; j < 4; ++j) {
                    float p = __expf(s4[j][r] - mn);
                    s4[j][r] = p;
                    ps += p;
                }
                #pragma unroll
                for (int o = 1; o < 16; o <<= 1) ps += __shfl_xor(ps, o);
                l[r] = l[r] * corr + ps;
                m[r] = mn;
                #pragma unroll
                for (int j = 0; j < 4; ++j) o4[j][r] *= corr;
            }

            // ---- P: pack (hi|lo) u32, wave-private LDS round-trip ----
            #pragma unroll
            for (int j = 0; j < 4; ++j)
                #pragma unroll
                for (int r = 0; r < 4; ++r) {
                    float p = s4[j][r];
                    ushort_t hi = f2bf(p);
                    ushort_t lo = f2bf(p - bf2f(hi));
                    Ps[pbase + (g * 4 + r) * 68 + c + j * 16] =
                        (unsigned int)hi | ((unsigned int)lo << 16);
                }
            asm volatile("s_waitcnt lgkmcnt(0)" ::: "memory");
            __builtin_amdgcn_sched_barrier(0);     // rule #18

            s16x8 pah[2], pal[2];
            #pragma unroll
            for (int ks = 0; ks < 2; ++ks) {
                uint4 a = *(const uint4*)&Ps[pbase + c * 68 + ks * 32 + g * 8];
                uint4 bq = *(const uint4*)&Ps[pbase + c * 68 + ks * 32 + g * 8 + 4];
                unsigned int wd[8] = {a.x, a.y, a.z, a.w, bq.x, bq.y, bq.z, bq.w};
                union { unsigned int u[4]; s16x8 v; } uh, ul;
                #pragma unroll
                for (int t = 0; t < 4; ++t) {
                    uh.u[t] = (wd[2 * t] & 0xffffu) | (wd[2 * t + 1] << 16);
                    ul.u[t] = (wd[2 * t] >> 16) | (wd[2 * t + 1] & 0xffff0000u);
                }
                pah[ks] = uh.v;
                pal[ks] = ul.v;
            }

            // ---- O += P V  (cols d = c + j*16) ----
            __builtin_amdgcn_s_setprio(1);
            #pragma unroll
            for (int j = 0; j < 4; ++j)
                #pragma unroll
                for (int ks = 0; ks < 2; ++ks) {
                    s16x8 vfh = *(const s16x8*)&Vhs[(c + j * 16) * 72 + ks * 32 + g * 8];
                    s16x8 vfl = *(const s16x8*)&Vls[(c + j * 16) * 72 + ks * 32 + g * 8];
                    o4[j] = __builtin_amdgcn_mfma_f32_16x16x32_bf16(pah[ks], vfh, o4[j], 0, 0, 0);
                    o4[j] = __builtin_amdgcn_mfma_f32_16x16x32_bf16(pah[ks], vfl, o4[j], 0, 0, 0);
                    o4[j] = __builtin_amdgcn_mfma_f32_16x16x32_bf16(pal[ks], vfh, o4[j], 0, 0, 0);
                }
            __builtin_amdgcn_s_setprio(0);
        }
        __syncthreads();   // before next tile's staging overwrites K/V LDS
    }

    // ---- epilogue: scale 1/l, split to bf16 hi/lo ctx ----
    float inv[4];
    #pragma unroll
    for (int r = 0; r < 4; ++r) inv[r] = 1.f / l[r];
    #pragma unroll
    for (int j = 0; j < 4; ++j)
        #pragma unroll
        for (int r = 0; r < 4; ++r) {
            float val = o4[j][r] * inv[r];
            int tok = b * S_ + q0 + w * 16 + g * 4 + r;
            int col = h * 64 + c + j * 16;
            ushort_t hi = f2bf(val);
            ch[(size_t)tok * 1024 + col] = hi;
            cl[(size_t)tok * 1024 + col] = f2bf(val - bf2f(hi));
        }
}

// ---------------------------------------------------------------------------
extern "C" void kernel_launch(void* const* d_in, const int* in_sizes, int n_in,
                              void* d_out, int out_size, void* d_ws, size_t ws_size,
                              hipStream_t stream)
{
    const float* x    = (const float*)d_in[0];
    const float* Wq   = (const float*)d_in[1];  const float* bq   = (const float*)d_in[2];
    const float* Wk   = (const float*)d_in[3];  const float* bk   = (const float*)d_in[4];
    const float* Wv   = (const float*)d_in[5];  const float* bv   = (const float*)d_in[6];
    const float* Wo   = (const float*)d_in[7];  const float* bo   = (const float*)d_in[8];
    const float* dpw1 = (const float*)d_in[9];  const float* dpb1 = (const float*)d_in[10];
    const float* lng  = (const float*)d_in[11]; const float* lnb  = (const float*)d_in[12];
    const float* dpw2 = (const float*)d_in[13]; const float* dpb2 = (const float*)d_in[14];
    const float* gw1  = (const float*)d_in[15]; const float* gb1  = (const float*)d_in[16];
    const float* gw2  = (const float*)d_in[17]; const float* gb2  = (const float*)d_in[18];
    float* out = (float*)d_out;

    // ---- workspace layout ----
    float* ws   = (float*)d_ws;
    float* v32  = ws;                                  // 4096x1024 fp32
    float* h32  = v32 + (size_t)MTOK * E_;             // 4096x512  fp32
    float* bcat = h32 + (size_t)MTOK * HID;            // 3584
    float* gate = bcat + NCAT;                         // 4096
    ushort_t* bp   = (ushort_t*)(gate + MTOK);
    ushort_t* xh   = bp;                               // 4096x1024 (-> ch)
    ushort_t* xl   = xh  + (size_t)MTOK * E_;          // 4096x1024 (-> cl)
    ushort_t* bth  = xl  + (size_t)MTOK * E_;          // 3584x1024
    ushort_t* btl  = bth + (size_t)NCAT * E_;
    ushort_t* woth = btl + (size_t)NCAT * E_;          // 1024x1024
    ushort_t* wotl = woth + (size_t)E_ * E_;
    ushort_t* Qhb  = wotl + (size_t)E_ * E_;           // 4096x1024 each
    ushort_t* Qlb  = Qhb + (size_t)MTOK * E_;
    ushort_t* Khb  = Qlb + (size_t)MTOK * E_;
    ushort_t* Klb  = Khb + (size_t)MTOK * E_;
    ushort_t* Vthb = Klb + (size_t)MTOK * E_;          // 32x64x2048 each
    ushort_t* Vtlb = Vthb + (size_t)MTOK * E_;
    ushort_t* chb  = xh;                               // alias (x dead after GEMM1)
    ushort_t* clb  = xl;

    // 1) preprocessing: x split, weight transpose/splits, bias concat
    hipLaunchKernelGGL(split_kernel, dim3(4096), dim3(256), 0, stream,
                       x, xh, xl, MTOK * E_ / 4);
    hipLaunchKernelGGL(transpose_split_kernel, dim3(32, 32), dim3(256), 0, stream,
                       Wq, E_, bth, btl);
    hipLaunchKernelGGL(transpose_split_kernel, dim3(32, 32), dim3(256), 0, stream,
                       Wk, E_, bth + (size_t)1024 * E_, btl + (size_t)1024 * E_);
    hipLaunchKernelGGL(transpose_split_kernel, dim3(32, 32), dim3(256), 0, stream,
                       Wv, E_, bth + (size_t)2048 * E_, btl + (size_t)2048 * E_);
    hipLaunchKernelGGL(transpose_split_kernel, dim3(32, 16), dim3(256), 0, stream,
                       dpw1, HID, bth + (size_t)3072 * E_, btl + (size_t)3072 * E_);
    hipLaunchKernelGGL(transpose_split_kernel, dim3(32, 32), dim3(256), 0, stream,
                       Wo, E_, woth, wotl);
    hipLaunchKernelGGL(concat_bias_kernel, dim3(14), dim3(256), 0, stream,
                       bq, bk, bv, dpb1, bcat);

    // 2) fused QKV+h GEMM with routing epilogue (Q/K bf16, V/h fp32 compact)
    hipLaunchKernelGGL(mfma_gemm_qkvh_kernel, dim3(28, 32), dim3(256), 0, stream,
                       xh, xl, bth, btl, bcat, Qhb, Qlb, Khb, Klb, v32, h32);

    // 3) drift tail -> gate ; gated V transpose
    hipLaunchKernelGGL(ln_gate_kernel, dim3(MTOK / 4), dim3(256), 0, stream,
                       h32, lng, lnb, dpw2, dpb2, gw1, gb1, gw2, gb2, gate);
    hipLaunchKernelGGL(v_transpose_kernel, dim3(32, 32), dim3(256), 0, stream,
                       v32, gate, Vthb, Vtlb);

    // 4) MFMA causal gated attention (QB=128, 8 waves) -> ctx bf16 hi/lo
    hipLaunchKernelGGL(attn_mfma_kernel, dim3(S_ / 128, B_ * NH), dim3(512), 0, stream,
                       Qhb, Qlb, Khb, Klb, Vthb, Vtlb, chb, clb);

    // 5) output projection
    hipLaunchKernelGGL(mfma_gemm_kernel, dim3(E_ / 128, MTOK / 128), dim3(256), 0, stream,
                       chb, clb, woth, wotl, bo, out, E_, E_);
}

// Round 7
// 396.247 us; speedup vs baseline: 1.1286x; 1.1286x over previous
//
#include <hip/hip_runtime.h>
#include <math.h>
#include <stdint.h>

#define B_   2
#define S_   2048
#define E_   1024
#define NH   16
#define DH   64
#define HID  512
#define NCAT 3584            // Q(1024) + K(1024) + V(1024) + h(512)
#define MTOK 4096            // B_*S_

typedef unsigned short ushort_t;
typedef short  s16x8  __attribute__((ext_vector_type(8)));
typedef unsigned short us4 __attribute__((ext_vector_type(4)));
typedef float  f32x4  __attribute__((ext_vector_type(4)));

static constexpr float LN_EPS    = 1e-5f;
static constexpr float SCALE     = 0.125f;   // Dh^-0.5
static constexpr float INV_SQRT2 = 0.70710678118654752440f;

__device__ __forceinline__ float gelu_exact(float v) {
    return 0.5f * v * (1.0f + erff(v * INV_SQRT2));
}

// fp32 <-> bf16 bits (RNE)
__device__ __forceinline__ ushort_t f2bf(float f) {
    unsigned int u = __float_as_uint(f);
    unsigned int r = u + 0x7fffu + ((u >> 16) & 1u);
    return (ushort_t)(r >> 16);
}
__device__ __forceinline__ float bf2f(ushort_t s) {
    return __uint_as_float(((unsigned int)s) << 16);
}

// async global->LDS 16B per lane; LDS dest is wave-uniform base + lane*16
__device__ __forceinline__ void stage16(const void* g, void* ldsbase) {
#if __has_builtin(__builtin_amdgcn_global_load_lds)
    __builtin_amdgcn_global_load_lds(
        (const __attribute__((address_space(1))) void*)g,
        (__attribute__((address_space(3))) void*)ldsbase, 16, 0, 0);
#else
    ((uint4*)ldsbase)[threadIdx.x & 63] = *(const uint4*)g;
#endif
}

// T1: XCD-chunked bijective block swizzle (requires total % 8 == 0).
__device__ __forceinline__ void xcd_swizzle(int gx, int gy, int& bx, int& by) {
    const int T = gx * gy;
    const int lin = blockIdx.y * gx + blockIdx.x;
    const int work = (lin & 7) * (T >> 3) + (lin >> 3);
    bx = work % gx;
    by = work / gx;
}

// ---------------------------------------------------------------------------
// Fused preprocessing: x hi/lo split + 5 weight transpose/splits + bias concat
// Block ranges: [0,1024) x-split; [1024,2048) Wq; [2048,3072) Wk;
// [3072,4096) Wv; [4096,5120) Wo; [5120,5632) dp_w1; [5632,5646) bias.
// ---------------------------------------------------------------------------
__global__ __launch_bounds__(256) void preproc_kernel(
    const float* __restrict__ x,
    const float* __restrict__ Wq, const float* __restrict__ Wk,
    const float* __restrict__ Wv, const float* __restrict__ Wo,
    const float* __restrict__ dpw1,
    const float* __restrict__ bq, const float* __restrict__ bk,
    const float* __restrict__ bv, const float* __restrict__ b1,
    ushort_t* __restrict__ xh, ushort_t* __restrict__ xl,
    ushort_t* __restrict__ bth, ushort_t* __restrict__ btl,
    ushort_t* __restrict__ woth, ushort_t* __restrict__ wotl,
    float* __restrict__ bcat)
{
    __shared__ float tile[32][33];
    int bid = blockIdx.x;
    const int t = threadIdx.x;

    if (bid < 1024) {                       // ---- x split ----
        int base = bid * 1024 + t;          // f32x4 index
        #pragma unroll
        for (int it = 0; it < 4; ++it) {
            int i = base + it * 256;
            float4 v = ((const float4*)x)[i];
            float vv[4] = {v.x, v.y, v.z, v.w};
            us4 h, l;
            #pragma unroll
            for (int j = 0; j < 4; ++j) {
                ushort_t hh = f2bf(vv[j]);
                h[j] = hh;
                l[j] = f2bf(vv[j] - bf2f(hh));
            }
            *(us4*)&xh[(size_t)i * 4] = h;
            *(us4*)&xl[(size_t)i * 4] = l;
        }
        return;
    }
    bid -= 1024;
    if (bid < 4608) {                       // ---- weight transposes ----
        const float* W; ushort_t *th, *tl; int N, kx, ny;
        if (bid < 1024)      { W = Wq;   th = bth;                        tl = btl;                        N = 1024; kx = bid & 31; ny = bid >> 5; }
        else if (bid < 2048) { W = Wk;   th = bth + (size_t)1024 * E_;    tl = btl + (size_t)1024 * E_;    N = 1024; kx = (bid - 1024) & 31; ny = (bid - 1024) >> 5; }
        else if (bid < 3072) { W = Wv;   th = bth + (size_t)2048 * E_;    tl = btl + (size_t)2048 * E_;    N = 1024; kx = (bid - 2048) & 31; ny = (bid - 2048) >> 5; }
        else if (bid < 4096) { W = Wo;   th = woth;                       tl = wotl;                       N = 1024; kx = (bid - 3072) & 31; ny = (bid - 3072) >> 5; }
        else                 { W = dpw1; th = bth + (size_t)3072 * E_;    tl = btl + (size_t)3072 * E_;    N = 512;  kx = (bid - 4096) & 31; ny = (bid - 4096) >> 5; }

        const int k0 = kx * 32, n0 = ny * 32;
        const int r = t >> 3, c4 = (t & 7) * 4;
        float4 v = *(const float4*)&W[(size_t)(k0 + r) * N + n0 + c4];
        tile[r][c4 + 0] = v.x; tile[r][c4 + 1] = v.y;
        tile[r][c4 + 2] = v.z; tile[r][c4 + 3] = v.w;
        __syncthreads();
        us4 h, l;
        #pragma unroll
        for (int i = 0; i < 4; ++i) {
            float xv = tile[c4 + i][r];
            ushort_t hh = f2bf(xv);
            h[i] = hh;
            l[i] = f2bf(xv - bf2f(hh));
        }
        *(us4*)&th[(size_t)(n0 + r) * E_ + k0 + c4] = h;
        *(us4*)&tl[(size_t)(n0 + r) * E_ + k0 + c4] = l;
        return;
    }
    bid -= 4608;                            // ---- bias concat (14 blocks) ----
    int i = bid * 256 + t;
    if (i >= NCAT) return;
    float v;
    if      (i < 1024) v = bq[i];
    else if (i < 2048) v = bk[i - 1024];
    else if (i < 3072) v = bv[i - 2048];
    else               v = b1[i - 3072];
    bcat[i] = v;
}

// ---------------------------------------------------------------------------
// Shared GEMM core: 128x128 tile, BK=32, 4 waves, bf16x3 MFMA emulation,
// m97 structure (global_load_lds 16B staging).  acc = (Ah+Al)(Bh+Bl)^T.
// ---------------------------------------------------------------------------
struct GemmCtx {
    int lane, w, wr, wc;
};

__device__ __forceinline__ void gemm_core(
    const ushort_t* __restrict__ Ah, const ushort_t* __restrict__ Al,
    const ushort_t* __restrict__ Bh, const ushort_t* __restrict__ Bl,
    int row0, int col0, int Kd,
    ushort_t* Ahs, ushort_t* Als, ushort_t* Bhs, ushort_t* Bls,
    f32x4 (&acc)[4][4], const GemmCtx& cx)
{
    const int lr = cx.lane >> 2;          // row within 16-row staging chunk
    const int lc = (cx.lane & 3) * 8;     // bf16 col offset (16B chunk)

    for (int k0 = 0; k0 < Kd; k0 += 32) {
        #pragma unroll
        for (int ii = 0; ii < 2; ++ii) {
            const int r0 = (cx.w * 2 + ii) * 16;
            const size_t ga = (size_t)(row0 + r0 + lr) * Kd + k0 + lc;
            const size_t gb = (size_t)(col0 + r0 + lr) * Kd + k0 + lc;
            stage16(Ah + ga, &Ahs[r0 * 32]);
            stage16(Al + ga, &Als[r0 * 32]);
            stage16(Bh + gb, &Bhs[r0 * 32]);
            stage16(Bl + gb, &Bls[r0 * 32]);
        }
        __syncthreads();

        const int rA = cx.wr * 64 + (cx.lane & 15);
        const int rB = cx.wc * 64 + (cx.lane & 15);
        const int kq = (cx.lane >> 4) * 8;
        s16x8 fah[4], fal[4], fbh[4], fbl[4];
        #pragma unroll
        for (int i = 0; i < 4; ++i) {
            fah[i] = *(const s16x8*)&Ahs[(rA + i * 16) * 32 + kq];
            fal[i] = *(const s16x8*)&Als[(rA + i * 16) * 32 + kq];
            fbh[i] = *(const s16x8*)&Bhs[(rB + i * 16) * 32 + kq];
            fbl[i] = *(const s16x8*)&Bls[(rB + i * 16) * 32 + kq];
        }
        __builtin_amdgcn_s_setprio(1);
        #pragma unroll
        for (int i = 0; i < 4; ++i)
            #pragma unroll
            for (int j = 0; j < 4; ++j) {
                acc[i][j] = __builtin_amdgcn_mfma_f32_16x16x32_bf16(fah[i], fbh[j], acc[i][j], 0, 0, 0);
                acc[i][j] = __builtin_amdgcn_mfma_f32_16x16x32_bf16(fah[i], fbl[j], acc[i][j], 0, 0, 0);
                acc[i][j] = __builtin_amdgcn_mfma_f32_16x16x32_bf16(fal[i], fbh[j], acc[i][j], 0, 0, 0);
            }
        __builtin_amdgcn_s_setprio(0);
        __syncthreads();
    }
}

// ---------------------------------------------------------------------------
// GEMM1: x @ [Wq|Wk|Wv|dp_w1] with fused routing epilogue.
// ---------------------------------------------------------------------------
__global__ __launch_bounds__(256) void mfma_gemm_qkvh_kernel(
    const ushort_t* __restrict__ Ah, const ushort_t* __restrict__ Al,
    const ushort_t* __restrict__ Bh, const ushort_t* __restrict__ Bl,
    const float* __restrict__ bias,
    ushort_t* __restrict__ Qh, ushort_t* __restrict__ Ql,
    ushort_t* __restrict__ Kh, ushort_t* __restrict__ Kl,
    float* __restrict__ v32, float* __restrict__ h32)
{
    __shared__ __align__(16) ushort_t Ahs[128 * 32];
    __shared__ __align__(16) ushort_t Als[128 * 32];
    __shared__ __align__(16) ushort_t Bhs[128 * 32];
    __shared__ __align__(16) ushort_t Bls[128 * 32];

    int bx, by;
    xcd_swizzle(28, 32, bx, by);               // 896 blocks = 8 x 112
    const int row0 = by * 128, col0 = bx * 128;

    GemmCtx cx;
    cx.lane = threadIdx.x & 63;
    cx.w    = threadIdx.x >> 6;
    cx.wr   = cx.w >> 1; cx.wc = cx.w & 1;

    f32x4 acc[4][4] = {};
    gemm_core(Ah, Al, Bh, Bl, row0, col0, E_, Ahs, Als, Bhs, Bls, acc, cx);

    const int crow = row0 + cx.wr * 64 + ((cx.lane >> 4) * 4);
    const int ccol0 = col0 + cx.wc * 64 + (cx.lane & 15);

    #pragma unroll
    for (int j = 0; j < 4; ++j) {
        const int gcol = ccol0 + j * 16;
        const float bv = bias[gcol];
        #pragma unroll
        for (int i = 0; i < 4; ++i)
            #pragma unroll
            for (int r = 0; r < 4; ++r) {
                const int row = crow + i * 16 + r;
                float val = acc[i][j][r] + bv;
                if (gcol < 1024) {            // Q (pre-scaled)
                    val *= SCALE;
                    ushort_t hi = f2bf(val);
                    Qh[(size_t)row * 1024 + gcol] = hi;
                    Ql[(size_t)row * 1024 + gcol] = f2bf(val - bf2f(hi));
                } else if (gcol < 2048) {     // K
                    ushort_t hi = f2bf(val);
                    Kh[(size_t)row * 1024 + gcol - 1024] = hi;
                    Kl[(size_t)row * 1024 + gcol - 1024] = f2bf(val - bf2f(hi));
                } else if (gcol < 3072) {     // V (fp32; gate folded later)
                    v32[(size_t)row * 1024 + gcol - 2048] = val;
                } else {                      // h (drift-probe)
                    h32[(size_t)row * 512 + gcol - 3072] = val;
                }
            }
    }
}

// ---------------------------------------------------------------------------
// GEMM2 (Wo): plain fp32-out GEMM with bias
// ---------------------------------------------------------------------------
__global__ __launch_bounds__(256) void mfma_gemm_kernel(
    const ushort_t* __restrict__ Ah, const ushort_t* __restrict__ Al,
    const ushort_t* __restrict__ Bh, const ushort_t* __restrict__ Bl,
    const float* __restrict__ bias,
    float* __restrict__ C, int N, int Kd)
{
    __shared__ __align__(16) ushort_t Ahs[128 * 32];
    __shared__ __align__(16) ushort_t Als[128 * 32];
    __shared__ __align__(16) ushort_t Bhs[128 * 32];
    __shared__ __align__(16) ushort_t Bls[128 * 32];

    int bx, by;
    xcd_swizzle(gridDim.x, gridDim.y, bx, by);
    const int row0 = by * 128, col0 = bx * 128;

    GemmCtx cx;
    cx.lane = threadIdx.x & 63;
    cx.w    = threadIdx.x >> 6;
    cx.wr   = cx.w >> 1; cx.wc = cx.w & 1;

    f32x4 acc[4][4] = {};
    gemm_core(Ah, Al, Bh, Bl, row0, col0, Kd, Ahs, Als, Bhs, Bls, acc, cx);

    const int crow = row0 + cx.wr * 64 + ((cx.lane >> 4) * 4);
    const int ccol = col0 + cx.wc * 64 + (cx.lane & 15);
    #pragma unroll
    for (int j = 0; j < 4; ++j) {
        const float bv = bias[ccol + j * 16];
        #pragma unroll
        for (int i = 0; i < 4; ++i)
            #pragma unroll
            for (int r = 0; r < 4; ++r)
                C[(size_t)(crow + i * 16 + r) * N + ccol + j * 16] = acc[i][j][r] + bv;
    }
}

// ---------------------------------------------------------------------------
// Per-row drift tail: LN(h32) -> GELU -> @dp_w2 -> tiny MLP -> tanh = gate
// ---------------------------------------------------------------------------
__global__ __launch_bounds__(256) void ln_gate_kernel(
    const float* __restrict__ h32,
    const float* __restrict__ lng, const float* __restrict__ lnb,
    const float* __restrict__ w2,  const float* __restrict__ b2,
    const float* __restrict__ gw1, const float* __restrict__ gb1,
    const float* __restrict__ gw2, const float* __restrict__ gb2,
    float* __restrict__ gate)
{
    const int row  = blockIdx.x * 4 + (threadIdx.x >> 6);
    const int lane = threadIdx.x & 63;
    const float* h = h32 + (size_t)row * 512;

    float4 a = *(const float4*)&h[lane * 4];
    float4 b = *(const float4*)&h[256 + lane * 4];
    float va[8] = {a.x, a.y, a.z, a.w, b.x, b.y, b.z, b.w};

    float sum = 0.f, sq = 0.f;
    #pragma unroll
    for (int j = 0; j < 8; ++j) { sum += va[j]; sq += va[j] * va[j]; }
    #pragma unroll
    for (int o = 1; o < 64; o <<= 1) {
        sum += __shfl_xor(sum, o);
        sq  += __shfl_xor(sq,  o);
    }
    const float mu  = sum * (1.f / HID);
    const float inv = 1.f / sqrtf(sq * (1.f / HID) - mu * mu + LN_EPS);

    float4 g0 = *(const float4*)&lng[lane * 4];
    float4 g1 = *(const float4*)&lng[256 + lane * 4];
    float4 o0 = *(const float4*)&lnb[lane * 4];
    float4 o1 = *(const float4*)&lnb[256 + lane * 4];
    float4 w0 = *(const float4*)&w2[lane * 4];
    float4 w1 = *(const float4*)&w2[256 + lane * 4];
    float gg[8] = {g0.x, g0.y, g0.z, g0.w, g1.x, g1.y, g1.z, g1.w};
    float bb[8] = {o0.x, o0.y, o0.z, o0.w, o1.x, o1.y, o1.z, o1.w};
    float ww[8] = {w0.x, w0.y, w0.z, w0.w, w1.x, w1.y, w1.z, w1.w};

    float part = 0.f;
    #pragma unroll
    for (int j = 0; j < 8; ++j) {
        float nx = (va[j] - mu) * inv * gg[j] + bb[j];
        part += gelu_exact(nx) * ww[j];
    }
    #pragma unroll
    for (int o = 1; o < 64; o <<= 1) part += __shfl_xor(part, o);

    if (lane == 0) {
        float drift = part + b2[0];
        float gacc = gb2[0];
        #pragma unroll
        for (int i = 0; i < 16; ++i) {
            float tt = fmaf(drift, gw1[i], gb1[i]);
            gacc = fmaf(gelu_exact(tt), gw2[i], gacc);
        }
        gate[row] = tanhf(gacc);
    }
}

// ---------------------------------------------------------------------------
// v32 [4096][1024] -> gated, transposed per head: Vt[bh][d=64][S=2048] hi/lo
// ---------------------------------------------------------------------------
__global__ __launch_bounds__(256) void v_transpose_kernel(
    const float* __restrict__ v32, const float* __restrict__ gate,
    ushort_t* __restrict__ Vth, ushort_t* __restrict__ Vtl)
{
    __shared__ float T[64 * 68];
    const int kt = blockIdx.x, bh = blockIdx.y;
    const int b = bh >> 4, h = bh & 15;
    const int tid = threadIdx.x;

    #pragma unroll
    for (int it = 0; it < 4; ++it) {
        int idx = tid + it * 256;                  // 0..1023
        int tokr = idx >> 4, f4 = idx & 15;
        int tok = b * S_ + kt * 64 + tokr;
        float g = gate[tok];
        float4 v = *(const float4*)&v32[(size_t)tok * 1024 + h * 64 + f4 * 4];
        T[(f4 * 4 + 0) * 68 + tokr] = v.x * g;
        T[(f4 * 4 + 1) * 68 + tokr] = v.y * g;
        T[(f4 * 4 + 2) * 68 + tokr] = v.z * g;
        T[(f4 * 4 + 3) * 68 + tokr] = v.w * g;
    }
    __syncthreads();

    const int d = tid >> 2, t0 = (tid & 3) * 16;
    const size_t obase = (size_t)bh * 64 * S_ + (size_t)d * S_ + kt * 64 + t0;
    s16x8 h8[2], l8[2];
    #pragma unroll
    for (int u = 0; u < 16; ++u) {
        float f = T[d * 68 + t0 + u];
        ushort_t hh = f2bf(f);
        h8[u >> 3][u & 7] = (short)hh;
        l8[u >> 3][u & 7] = (short)f2bf(f - bf2f(hh));
    }
    *(s16x8*)&Vth[obase]     = h8[0];
    *(s16x8*)&Vth[obase + 8] = h8[1];
    *(s16x8*)&Vtl[obase]     = l8[0];
    *(s16x8*)&Vtl[obase + 8] = l8[1];
}

// ---------------------------------------------------------------------------
// MFMA causal flash attention v3 (bf16 hi/lo x3 emu), QB=128, 8 waves.
// SWAPPED QK^T: s = mfma(K, Q) -> lane holds 16 scores for q = lane&15.
// Softmax lane-local (2 shfl_xor); P packed via v_cvt_pk_bf16_f32 into
// frag-layout LDS (XOR-swizzled, zero unpack); exact defer-rescale;
// Q frags direct from global (no Q LDS); T1/T5/T14 kept.
// ---------------------------------------------------------------------------
__global__ __launch_bounds__(512, 4) void attn_mfma_kernel(
    const ushort_t* __restrict__ Qh, const ushort_t* __restrict__ Ql,
    const ushort_t* __restrict__ Kh, const ushort_t* __restrict__ Kl,
    const ushort_t* __restrict__ Vth, const ushort_t* __restrict__ Vtl,
    ushort_t* __restrict__ ch, ushort_t* __restrict__ cl)
{
    __shared__ __align__(16) ushort_t Khs[64 * 72], Kls[64 * 72];
    __shared__ __align__(16) ushort_t Vhs[64 * 72], Vls[64 * 72];
    __shared__ __align__(16) unsigned int Ph[8 * 16 * 32];   // per-wave [16 q][32 kp]
    __shared__ __align__(16) unsigned int Pl[8 * 16 * 32];

    const int tid  = threadIdx.x;
    const int lane = tid & 63;
    const int w    = tid >> 6;       // 0..7
    const int g    = lane >> 4;      // 0..3
    const int c    = lane & 15;      // 0..15

    // T1: 512 blocks = 8 XCD chunks of 64
    const int lin  = blockIdx.y * 16 + blockIdx.x;
    const int work = (lin & 7) * 64 + (lin >> 3);
    const int bh   = work >> 4;
    const int qt   = 15 - (work & 15);             // heavy diagonal first
    const int b    = bh >> 4, h = bh & 15;
    const int q0   = qt * 128;

    const size_t qkb = (size_t)b * S_ * 1024 + h * 64;   // [token][1024] slice
    const size_t vtb = (size_t)bh * 64 * S_;             // [d][2048]

    const int qwave = q0 + w * 16;             // wave's first q row

    // Q fragments direct from global: B-operand, q = qwave + c, d-slice ks*32+g*8
    const size_t qrow = qkb + (size_t)(qwave + c) * 1024;
    s16x8 qfh[2], qfl[2];
    qfh[0] = *(const s16x8*)&Qh[qrow + g * 8];
    qfh[1] = *(const s16x8*)&Qh[qrow + 32 + g * 8];
    qfl[0] = *(const s16x8*)&Ql[qrow + g * 8];
    qfl[1] = *(const s16x8*)&Ql[qrow + 32 + g * 8];

    f32x4 o4[4] = {};
    float m = -INFINITY, l = 0.f;              // per-lane state for q = qwave + c

    // P-LDS index: per-wave region, XOR swizzle keeps b128 reads spread
    #define PIDX(c_, kp_) ((w << 9) + ((c_) << 5) + ((kp_) ^ (((c_) & 7) << 2)))

    const int srow = tid >> 3, ssl = tid & 7;   // staging: 512 slots = 64x8

    // prefetch K/V tile 0 into registers (T14)
    s16x8 pkh, pkl, pvh, pvl;
    pkh = *(const s16x8*)&Kh [qkb + (size_t)srow * 1024 + ssl * 8];
    pkl = *(const s16x8*)&Kl [qkb + (size_t)srow * 1024 + ssl * 8];
    pvh = *(const s16x8*)&Vth[vtb + (size_t)srow * S_ + ssl * 8];
    pvl = *(const s16x8*)&Vtl[vtb + (size_t)srow * S_ + ssl * 8];

    const int ktmax = 2 * qt + 1;              // keys up to q0+127

    for (int kt = 0; kt <= ktmax; ++kt) {
        const int k0 = kt * 64;
        *(s16x8*)&Khs[srow * 72 + ssl * 8] = pkh;
        *(s16x8*)&Kls[srow * 72 + ssl * 8] = pkl;
        *(s16x8*)&Vhs[srow * 72 + ssl * 8] = pvh;
        *(s16x8*)&Vls[srow * 72 + ssl * 8] = pvl;
        __syncthreads();

        if (kt < ktmax) {                      // T14 prefetch next tile
            const int kn = k0 + 64;
            pkh = *(const s16x8*)&Kh [qkb + (size_t)(kn + srow) * 1024 + ssl * 8];
            pkl = *(const s16x8*)&Kl [qkb + (size_t)(kn + srow) * 1024 + ssl * 8];
            pvh = *(const s16x8*)&Vth[vtb + (size_t)srow * S_ + kn + ssl * 8];
            pvl = *(const s16x8*)&Vtl[vtb + (size_t)srow * S_ + kn + ssl * 8];
        }

        if (k0 <= qwave + 15) {                // per-wave causal skip
            // ---- S^T = K Q^T: lane holds s4[j][r] = S[k0+j*16+g*4+r][qwave+c]
            f32x4 s4[4] = {};
            __builtin_amdgcn_s_setprio(1);
            #pragma unroll
            for (int j = 0; j < 4; ++j)
                #pragma unroll
                for (int ks = 0; ks < 2; ++ks) {
                    s16x8 kfh = *(const s16x8*)&Khs[(c + j * 16) * 72 + ks * 32 + g * 8];
                    s16x8 kfl = *(const s16x8*)&Kls[(c + j * 16) * 72 + ks * 32 + g * 8];
                    s4[j] = __builtin_amdgcn_mfma_f32_16x16x32_bf16(kfh, qfh[ks], s4[j], 0, 0, 0);
                    s4[j] = __builtin_amdgcn_mfma_f32_16x16x32_bf16(kfh, qfl[ks], s4[j], 0, 0, 0);
                    s4[j] = __builtin_amdgcn_mfma_f32_16x16x32_bf16(kfl, qfh[ks], s4[j], 0, 0, 0);
                }
            __builtin_amdgcn_s_setprio(0);

            // causal mask: key k0+j*16+g*4+r vs q qwave+c
            if (k0 + 63 > qwave) {
                #pragma unroll
                for (int j = 0; j < 4; ++j)
                    #pragma unroll
                    for (int r = 0; r < 4; ++r)
                        if (k0 + j * 16 + g * 4 + r > qwave + c)
                            s4[j][r] = -INFINITY;
            }

            // ---- lane-local softmax for q = qwave + c ----
            float pmax = -INFINITY;
            #pragma unroll
            for (int j = 0; j < 4; ++j)
                #pragma unroll
                for (int r = 0; r < 4; ++r) pmax = fmaxf(pmax, s4[j][r]);
            pmax = fmaxf(pmax, __shfl_xor(pmax, 16));
            pmax = fmaxf(pmax, __shfl_xor(pmax, 32));

            const bool nomax = __all(pmax <= m);   // corr == 1 exactly
            const float mn = nomax ? m : fmaxf(m, pmax);

            float ps = 0.f;
            #pragma unroll
            for (int j = 0; j < 4; ++j)
                #pragma unroll
                for (int r = 0; r < 4; ++r) {
                    float p = __expf(s4[j][r] - mn);
                    s4[j][r] = p;
                    ps += p;
                }
            ps += __shfl_xor(ps, 16);
            ps += __shfl_xor(ps, 32);

            if (nomax) {
                l += ps;
            } else {
                float corr = (m == -INFINITY) ? 0.f : __expf(m - mn);
                l = l * corr + ps;
                m = mn;
                #pragma unroll
                for (int r = 0; r < 4; ++r) {     // broadcast corr to o4 rows
                    int src = ((g << 4) | (g * 4 + r)) << 2;
                    float cr = __int_as_float(
                        __builtin_amdgcn_ds_bpermute(src, __float_as_int(corr)));
                    #pragma unroll
                    for (int j = 0; j < 4; ++j) o4[j][r] *= cr;
                }
            }

            // ---- pack P (hi/lo bf16 pairs) into frag-layout LDS ----
            #pragma unroll
            for (int j = 0; j < 4; ++j)
                #pragma unroll
                for (int p = 0; p < 2; ++p) {
                    float e  = s4[j][2 * p];
                    float od = s4[j][2 * p + 1];
                    unsigned int hi2, lo2;
                    asm volatile("v_cvt_pk_bf16_f32 %0, %1, %2"
                                 : "=v"(hi2) : "v"(e), "v"(od));
                    float ef = __uint_as_float(hi2 << 16);
                    float of = __uint_as_float(hi2 & 0xffff0000u);
                    float el = e - ef, ol = od - of;
                    asm volatile("v_cvt_pk_bf16_f32 %0, %1, %2"
                                 : "=v"(lo2) : "v"(el), "v"(ol));
                    const int kp = j * 8 + g * 2 + p;
                    Ph[PIDX(c, kp)] = hi2;
                    Pl[PIDX(c, kp)] = lo2;
                }
            asm volatile("s_waitcnt lgkmcnt(0)" ::: "memory");
            __builtin_amdgcn_sched_barrier(0);     // rule #18

            // ---- read P frags (already frag-format; zero unpack) ----
            union U4 { uint4 u; s16x8 v; };
            s16x8 pah[2], pal[2];
            #pragma unroll
            for (int ks = 0; ks < 2; ++ks) {
                U4 a, bb;
                a.u  = *(const uint4*)&Ph[PIDX(c, ks * 16 + g * 4)];
                bb.u = *(const uint4*)&Pl[PIDX(c, ks * 16 + g * 4)];
                pah[ks] = a.v;
                pal[ks] = bb.v;
            }

            // ---- O += P V  (cols d = c + j*16) ----
            __builtin_amdgcn_s_setprio(1);
            #pragma unroll
            for (int j = 0; j < 4; ++j)
                #pragma unroll
                for (int ks = 0; ks < 2; ++ks) {
                    s16x8 vfh = *(const s16x8*)&Vhs[(c + j * 16) * 72 + ks * 32 + g * 8];
                    s16x8 vfl = *(const s16x8*)&Vls[(c + j * 16) * 72 + ks * 32 + g * 8];
                    o4[j] = __builtin_amdgcn_mfma_f32_16x16x32_bf16(pah[ks], vfh, o4[j], 0, 0, 0);
                    o4[j] = __builtin_amdgcn_mfma_f32_16x16x32_bf16(pah[ks], vfl, o4[j], 0, 0, 0);
                    o4[j] = __builtin_amdgcn_mfma_f32_16x16x32_bf16(pal[ks], vfh, o4[j], 0, 0, 0);
                }
            __builtin_amdgcn_s_setprio(0);
        }
        __syncthreads();   // before next tile's staging overwrites K/V LDS
    }

    // ---- epilogue: fetch l for row q = g*4+r, scale, split hi/lo ----
    float inv[4];
    #pragma unroll
    for (int r = 0; r < 4; ++r) {
        int src = ((g << 4) | (g * 4 + r)) << 2;
        float lb = __int_as_float(
            __builtin_amdgcn_ds_bpermute(src, __float_as_int(l)));
        inv[r] = 1.f / lb;
    }
    #pragma unroll
    for (int j = 0; j < 4; ++j)
        #pragma unroll
        for (int r = 0; r < 4; ++r) {
            float val = o4[j][r] * inv[r];
            int tok = b * S_ + qwave + g * 4 + r;
            int col = h * 64 + c + j * 16;
            ushort_t hi = f2bf(val);
            ch[(size_t)tok * 1024 + col] = hi;
            cl[(size_t)tok * 1024 + col] = f2bf(val - bf2f(hi));
        }
    #undef PIDX
}

// ---------------------------------------------------------------------------
extern "C" void kernel_launch(void* const* d_in, const int* in_sizes, int n_in,
                              void* d_out, int out_size, void* d_ws, size_t ws_size,
                              hipStream_t stream)
{
    const float* x    = (const float*)d_in[0];
    const float* Wq   = (const float*)d_in[1];  const float* bq   = (const float*)d_in[2];
    const float* Wk   = (const float*)d_in[3];  const float* bk   = (const float*)d_in[4];
    const float* Wv   = (const float*)d_in[5];  const float* bv   = (const float*)d_in[6];
    const float* Wo   = (const float*)d_in[7];  const float* bo   = (const float*)d_in[8];
    const float* dpw1 = (const float*)d_in[9];  const float* dpb1 = (const float*)d_in[10];
    const float* lng  = (const float*)d_in[11]; const float* lnb  = (const float*)d_in[12];
    const float* dpw2 = (const float*)d_in[13]; const float* dpb2 = (const float*)d_in[14];
    const float* gw1  = (const float*)d_in[15]; const float* gb1  = (const float*)d_in[16];
    const float* gw2  = (const float*)d_in[17]; const float* gb2  = (const float*)d_in[18];
    float* out = (float*)d_out;

    // ---- workspace layout ----
    float* ws   = (float*)d_ws;
    float* v32  = ws;                                  // 4096x1024 fp32
    float* h32  = v32 + (size_t)MTOK * E_;             // 4096x512  fp32
    float* bcat = h32 + (size_t)MTOK * HID;            // 3584
    float* gate = bcat + NCAT;                         // 4096
    ushort_t* bp   = (ushort_t*)(gate + MTOK);
    ushort_t* xh   = bp;                               // 4096x1024 (-> ch)
    ushort_t* xl   = xh  + (size_t)MTOK * E_;          // 4096x1024 (-> cl)
    ushort_t* bth  = xl  + (size_t)MTOK * E_;          // 3584x1024
    ushort_t* btl  = bth + (size_t)NCAT * E_;
    ushort_t* woth = btl + (size_t)NCAT * E_;          // 1024x1024
    ushort_t* wotl = woth + (size_t)E_ * E_;
    ushort_t* Qhb  = wotl + (size_t)E_ * E_;           // 4096x1024 each
    ushort_t* Qlb  = Qhb + (size_t)MTOK * E_;
    ushort_t* Khb  = Qlb + (size_t)MTOK * E_;
    ushort_t* Klb  = Khb + (size_t)MTOK * E_;
    ushort_t* Vthb = Klb + (size_t)MTOK * E_;          // 32x64x2048 each
    ushort_t* Vtlb = Vthb + (size_t)MTOK * E_;
    ushort_t* chb  = xh;                               // alias (x dead after GEMM1)
    ushort_t* clb  = xl;

    // 1) fused preprocessing (x split + 5 transposes + bias concat)
    hipLaunchKernelGGL(preproc_kernel, dim3(5646), dim3(256), 0, stream,
                       x, Wq, Wk, Wv, Wo, dpw1, bq, bk, bv, dpb1,
                       xh, xl, bth, btl, woth, wotl, bcat);

    // 2) fused QKV+h GEMM with routing epilogue (Q/K bf16, V/h fp32 compact)
    hipLaunchKernelGGL(mfma_gemm_qkvh_kernel, dim3(28, 32), dim3(256), 0, stream,
                       xh, xl, bth, btl, bcat, Qhb, Qlb, Khb, Klb, v32, h32);

    // 3) drift tail -> gate ; gated V transpose
    hipLaunchKernelGGL(ln_gate_kernel, dim3(MTOK / 4), dim3(256), 0, stream,
                       h32, lng, lnb, dpw2, dpb2, gw1, gb1, gw2, gb2, gate);
    hipLaunchKernelGGL(v_transpose_kernel, dim3(32, 32), dim3(256), 0, stream,
                       v32, gate, Vthb, Vtlb);

    // 4) MFMA causal gated attention v3 -> ctx bf16 hi/lo
    hipLaunchKernelGGL(attn_mfma_kernel, dim3(S_ / 128, B_ * NH), dim3(512), 0, stream,
                       Qhb, Qlb, Khb, Klb, Vthb, Vtlb, chb, clb);

    // 5) output projection
    hipLaunchKernelGGL(mfma_gemm_kernel, dim3(E_ / 128, MTOK / 128), dim3(256), 0, stream,
                       chb, clb, woth, wotl, bo, out, E_, E_);
}